// Round 9
// baseline (452.254 us; speedup 1.0000x reference)
//
#include <hip/hip_runtime.h>
#include <hip/hip_bf16.h>

#define EPS_NORM 1e-12f
#define EPS_SM   1e-16f
#define SLOT     96        // padded CSR stride; >= max in-degree (Poisson(32), P(>96)~1e-19)
#define BSH      8         // bucket = 256 consecutive dst nodes
#define BRANGE   256
#define NBMAX    512       // LDS sizing (supports N <= 131072)
#define BCAP     9216      // per-bucket edge capacity: mean 8184, +11 sigma
#define TILE     8192      // edges per k_part block

typedef float f32x4 __attribute__((ext_vector_type(4)));

// ============ pass 1: partition edges into dst-range buckets (coalesced writes) ============
// packed entry: (src << 8) | (dst & 255)   [src < 2^17, so fits int32]
__global__ __launch_bounds__(1024) void k_part(const int* __restrict__ src,
        const int* __restrict__ dst, int* __restrict__ gcur, int* __restrict__ part,
        int E, int NB) {
    __shared__ int h[NBMAX];      // histogram -> inclusive scan (in place)
    __shared__ int c0[NBMAX];     // saved counts
    __shared__ int lo[NBMAX + 1]; // exclusive offsets within tile (+ sentinel)
    __shared__ int cur[NBMAX];    // staging cursor
    __shared__ int gb[NBMAX];     // global base for this block's chunk
    __shared__ int stage[TILE];
    int t = threadIdx.x;
    int tile0 = blockIdx.x * TILE;
    int n = E - tile0; if (n > TILE) n = TILE;

    for (int i = t; i < NBMAX; i += 1024) h[i] = 0;
    __syncthreads();
    for (int i = t; i < n; i += 1024)
        atomicAdd(&h[dst[tile0 + i] >> BSH], 1);
    __syncthreads();
    for (int i = t; i < NBMAX; i += 1024) c0[i] = h[i];
    __syncthreads();
    // inclusive Hillis-Steele scan over NBMAX slots (in place, read-sync-write)
    for (int d = 1; d < NBMAX; d <<= 1) {
        int v = (t < NBMAX && t >= d) ? h[t - d] : 0;
        __syncthreads();
        if (t < NBMAX) h[t] += v;
        __syncthreads();
    }
    if (t < NBMAX) { lo[t] = h[t] - c0[t]; cur[t] = h[t] - c0[t]; }
    if (t == 0) lo[NBMAX] = n;
    __syncthreads();
    // reserve global space: one atomic per (block, bucket)
    for (int i = t; i < NB; i += 1024)
        gb[i] = (c0[i] > 0) ? atomicAdd(&gcur[i], c0[i]) : 0;
    __syncthreads();
    // stage packed edges ordered by bucket
    for (int i = t; i < n; i += 1024) {
        int d = dst[tile0 + i];
        int s = src[tile0 + i];
        int b = d >> BSH;
        int p = atomicAdd(&cur[b], 1);
        stage[p] = (s << BSH) | (d & (BRANGE - 1));
    }
    __syncthreads();
    // copy out: contiguous chunk per bucket; binary search bucket of staged slot i
    for (int i = t; i < n; i += 1024) {
        int loB = 0, hiB = NB;          // invariant: lo[loB] <= i < lo[hiB]
        while (hiB - loB > 1) {
            int m = (loB + hiB) >> 1;
            if (lo[m] <= i) loB = m; else hiB = m;
        }
        int b = loB;
        int gpos = gb[b] + (i - lo[b]);
        if (gpos < BCAP)
            part[b * BCAP + gpos] = stage[i];
    }
}

// ============ pass 2: bucket -> padded CSR (one block per bucket; LDS positions) ============
__global__ __launch_bounds__(1024) void k_csr(const int* __restrict__ part,
        const int* __restrict__ gcur, int* __restrict__ csr, int* __restrict__ deg, int N) {
    __shared__ int cnt[BRANGE];
    int b = blockIdx.x, t = threadIdx.x;
    if (t < BRANGE) cnt[t] = 0;
    __syncthreads();
    int cntE = gcur[b]; if (cntE > BCAP) cntE = BCAP;
    const int* pb = part + b * BCAP;
    int n0 = b << BSH;
    for (int i = t; i < cntE; i += 1024) {
        int v = pb[i];
        int d = v & (BRANGE - 1);
        int s = v >> BSH;
        int p = atomicAdd(&cnt[d], 1);              // LDS atomic
        if (p < SLOT)
            csr[(size_t)(n0 + d) * SLOT + p] = s;   // random 4B within 98KB (L2-resident)
    }
    __syncthreads();
    if (t < BRANGE && n0 + t < N) deg[n0 + t] = cnt[t];
}

// ======================= h = relu(x @ W1 + b1), + inv-norm of h =======================
// thread-per-row, K split 4 ways across the block's 4 waves (wave q = K-quarter q).
// W1[k*16+c] is WAVE-UNIFORM -> compiler scalarizes to s_load; v_fma reads SGPR.
// Inner loop: 1 coalesced-strided f32x4 x-load + 64 v_fma. No LDS, no barrier in loop.
__global__ __launch_bounds__(256) void k_gemm1(const float* __restrict__ x,
        const float* __restrict__ W1, const float* __restrict__ b1,
        float* __restrict__ h, float* __restrict__ invn, int N) {
    __shared__ float red[4 * 64 * 20];   // [q][il][16 used of 20] -- 80B stride, 16B aligned
    int t = threadIdx.x;
    int q = t >> 6, il = t & 63;
    int rowu = blockIdx.x * 64 + il;
    int row = rowu < N ? rowu : N - 1;           // clamp (keeps control flow uniform)

    const float* xr = x + (size_t)row * 512 + q * 128;
    float acc[16];
#pragma unroll
    for (int c = 0; c < 16; ++c) acc[c] = 0.f;

#pragma unroll 4
    for (int kq = 0; kq < 32; ++kq) {
        f32x4 xv = *(const f32x4*)(xr + kq * 4);
        const float* wrow = W1 + (q * 128 + kq * 4) * 16;   // uniform address
#pragma unroll
        for (int kk = 0; kk < 4; ++kk) {
#pragma unroll
            for (int c = 0; c < 16; ++c)
                acc[c] += xv[kk] * wrow[kk * 16 + c];
        }
    }

    float* rp = red + (q * 64 + il) * 20;
#pragma unroll
    for (int j = 0; j < 4; ++j)
        *(f32x4*)(rp + j * 4) = *(const f32x4*)(acc + j * 4);
    __syncthreads();

    // reduce: thread t -> (row i2 = t>>2, col-chunk c4 = t&3); sum the 4 K-quarters
    int i2 = t >> 2, c4 = t & 3;
    int row2 = blockIdx.x * 64 + i2;
    f32x4 s = {0.f, 0.f, 0.f, 0.f};
#pragma unroll
    for (int q2 = 0; q2 < 4; ++q2) {
        f32x4 v = *(const f32x4*)(red + (q2 * 64 + i2) * 20 + c4 * 4);
        s.x += v.x; s.y += v.y; s.z += v.z; s.w += v.w;
    }
    const f32x4 bv = *(const f32x4*)(b1 + c4 * 4);
    s.x = fmaxf(s.x + bv.x, 0.f);
    s.y = fmaxf(s.y + bv.y, 0.f);
    s.z = fmaxf(s.z + bv.z, 0.f);
    s.w = fmaxf(s.w + bv.w, 0.f);
    float ss = s.x * s.x + s.y * s.y + s.z * s.z + s.w * s.w;
    ss += __shfl_xor(ss, 1); ss += __shfl_xor(ss, 2);   // sum over the 4 c4-lanes
    if (row2 < N) {
        *(f32x4*)(h + (size_t)row2 * 16 + c4 * 4) = s;
        if (c4 == 0) invn[row2] = 1.f / fmaxf(sqrtf(ss), EPS_NORM);
    }
}

// ======================= fused AGNN layer (padded-CSR gather, no atomics) =======================
__global__ __launch_bounds__(256) void k_agnn(const float* __restrict__ f,
        const float* __restrict__ inv, const int* __restrict__ deg,
        const int* __restrict__ csr, const float* __restrict__ beta,
        float* __restrict__ fout, float* __restrict__ invout, int N) {
    int wid = (blockIdx.x * 256 + threadIdx.x) >> 6;
    if (wid >= N) return;
    int lane = threadIdx.x & 63;
    int g = lane >> 4, k = lane & 15;

    float fd  = f[(size_t)wid * 16 + k];
    float ivd = inv[wid];
    float b   = beta[0];

    float sd = fd * fd;
    sd += __shfl_xor(sd, 1); sd += __shfl_xor(sd, 2);
    sd += __shfl_xor(sd, 4); sd += __shfl_xor(sd, 8);
    float pself = __expf(b * sd * ivd * ivd);
    float bs = b * ivd;

    int dg = deg[wid];
    int start = wid * SLOT;
    int end   = start + (dg < SLOT ? dg : SLOT);

    float sacc = 0.f, gacc = 0.f;
    for (int e = start + g; e < end; e += 8) {
        int  e1 = e + 4;
        bool v1 = e1 < end;
        int  si0 = csr[e];
        int  si1 = v1 ? csr[e1] : si0;
        float a0 = f[(size_t)si0 * 16 + k];
        float a1 = f[(size_t)si1 * 16 + k];
        float iv0 = inv[si0];
        float iv1 = inv[si1];
        float d0 = a0 * fd, d1 = a1 * fd;
        d0 += __shfl_xor(d0, 1); d1 += __shfl_xor(d1, 1);
        d0 += __shfl_xor(d0, 2); d1 += __shfl_xor(d1, 2);
        d0 += __shfl_xor(d0, 4); d1 += __shfl_xor(d1, 4);
        d0 += __shfl_xor(d0, 8); d1 += __shfl_xor(d1, 8);
        float p0 = __expf(bs * iv0 * d0);
        float p1 = v1 ? __expf(bs * iv1 * d1) : 0.f;
        sacc += p0 + p1;
        gacc += p0 * a0 + p1 * a1;
    }
    sacc += __shfl_xor(sacc, 16); sacc += __shfl_xor(sacc, 32);
    gacc += __shfl_xor(gacc, 16); gacc += __shfl_xor(gacc, 32);

    float denom = sacc + pself + EPS_SM;
    float outk  = (gacc + pself * fd) / denom;

    float ss = outk * outk;
    ss += __shfl_xor(ss, 1); ss += __shfl_xor(ss, 2);
    ss += __shfl_xor(ss, 4); ss += __shfl_xor(ss, 8);

    if (g == 0) {
        fout[(size_t)wid * 16 + k] = outk;
        if (k == 0) invout[wid] = 1.f / fmaxf(sqrtf(ss), EPS_NORM);
    }
}

// ======================= out = softmax(f @ W2 + b2) =======================
__global__ __launch_bounds__(256) void k_out(const float* __restrict__ f,
        const float* __restrict__ W2, const float* __restrict__ b2,
        float* __restrict__ out, int N) {
    __shared__ float w2s[16 * 40];
    __shared__ float b2s[40];
    for (int idx = threadIdx.x; idx < 16 * 40; idx += 256) w2s[idx] = W2[idx];
    if (threadIdx.x < 40) b2s[threadIdx.x] = b2[threadIdx.x];
    __syncthreads();
    int i = blockIdx.x * 256 + threadIdx.x;
    if (i >= N) return;
    const float4* fr = (const float4*)(f + (size_t)i * 16);
    float4 q0 = fr[0], q1 = fr[1], q2 = fr[2], q3 = fr[3];
    float fv[16] = {q0.x, q0.y, q0.z, q0.w, q1.x, q1.y, q1.z, q1.w,
                    q2.x, q2.y, q2.z, q2.w, q3.x, q3.y, q3.z, q3.w};
    float z[40];
#pragma unroll
    for (int c = 0; c < 40; ++c) z[c] = b2s[c];
#pragma unroll
    for (int k = 0; k < 16; ++k) {
        float fk = fv[k];
#pragma unroll
        for (int c = 0; c < 40; ++c) z[c] += fk * w2s[k * 40 + c];
    }
    float m = z[0];
#pragma unroll
    for (int c = 1; c < 40; ++c) m = fmaxf(m, z[c]);
    float ssum = 0.f;
#pragma unroll
    for (int c = 0; c < 40; ++c) { z[c] = __expf(z[c] - m); ssum += z[c]; }
    float is = 1.f / ssum;
    float* orow = out + (size_t)i * 40;
#pragma unroll
    for (int c = 0; c < 40; ++c) orow[c] = z[c] * is;
}

extern "C" void kernel_launch(void* const* d_in, const int* in_sizes, int n_in,
                              void* d_out, int out_size, void* d_ws, size_t ws_size,
                              hipStream_t stream) {
    const float* x    = (const float*)d_in[0];
    const int*   eidx = (const int*)d_in[1];
    const float* W1   = (const float*)d_in[2];
    const float* b1   = (const float*)d_in[3];
    const float* beta[3] = {(const float*)d_in[4], (const float*)d_in[5],
                            (const float*)d_in[6]};
    const float* W2   = (const float*)d_in[7];
    const float* b2   = (const float*)d_in[8];
    float*       out  = (float*)d_out;

    const int FIN = 512, H = 16;
    int N = in_sizes[0] / FIN;
    int E = in_sizes[1] / 2;
    int NB = (N + BRANGE - 1) >> BSH;           // 391 for N=100000

    const int* src = eidx;
    const int* dst = eidx + E;

    // workspace layout: csr[N*SLOT] | deg[N] | gcur[512] | part[NB*BCAP]
    // part is dead after k_csr -> overlay f0/f1/inv0/inv1 on it
    int*   csr  = (int*)d_ws;
    int*   degb = csr + (size_t)N * SLOT;
    int*   gcur = degb + N;
    int*   part = gcur + 512;
    float* f0   = (float*)part;
    float* f1   = f0 + (size_t)N * H;
    float* inv0 = f1 + (size_t)N * H;
    float* inv1 = inv0 + N;

    // ---- CSR build: bucket partition (coalesced) + per-bucket LDS-positioned fill
    hipMemsetAsync(gcur, 0, 512 * 4, stream);
    k_part<<<dim3((E + TILE - 1) / TILE), dim3(1024), 0, stream>>>(src, dst, gcur, part, E, NB);
    k_csr<<<dim3(NB), dim3(1024), 0, stream>>>(part, gcur, csr, degb, N);

    // ---- MLP in + 3 fused AGNN layers + MLP out  (k_gemm1 overwrites part region)
    k_gemm1<<<dim3((N + 63) / 64), dim3(256), 0, stream>>>(x, W1, b1, f0, inv0, N);

    float* fin = f0;  float* fout = f1;
    float* ivi = inv0; float* ivo = inv1;
    for (int l = 0; l < 3; ++l) {
        k_agnn<<<dim3((N + 3) / 4), dim3(256), 0, stream>>>(
            fin, ivi, degb, csr, beta[l], fout, ivo, N);
        float* t = fin; fin = fout; fout = t;
        t = ivi; ivi = ivo; ivo = t;
    }
    k_out<<<dim3((N + 255) / 256), dim3(256), 0, stream>>>(fin, W2, b2, out, N);
}

// Round 10
// 447.298 us; speedup vs baseline: 1.0111x; 1.0111x over previous
//
#include <hip/hip_runtime.h>
#include <hip/hip_bf16.h>

#define EPS_NORM 1e-12f
#define EPS_SM   1e-16f
#define SLOT     96        // padded CSR stride; >= max in-degree (Poisson(32), P(>96)~1e-19)
#define BSH      8         // bucket = 256 consecutive dst nodes
#define BRANGE   256
#define NBMAX    512       // LDS sizing (supports N <= 131072)
#define BCAP     9216      // per-bucket edge capacity: mean 8184, +11 sigma
#define TILE     8192      // edges per k_part block

typedef float f32x4 __attribute__((ext_vector_type(4)));

// ============ pass 1: partition edges into dst-range buckets (coalesced writes) ============
// packed entry: (src << 8) | (dst & 255)   [src < 2^17, so fits int32]
__global__ __launch_bounds__(1024) void k_part(const int* __restrict__ src,
        const int* __restrict__ dst, int* __restrict__ gcur, int* __restrict__ part,
        int E, int NB) {
    __shared__ int h[NBMAX];      // histogram -> inclusive scan (in place)
    __shared__ int c0[NBMAX];     // saved counts
    __shared__ int lo[NBMAX + 1]; // exclusive offsets within tile (+ sentinel)
    __shared__ int cur[NBMAX];    // staging cursor
    __shared__ int gb[NBMAX];     // global base for this block's chunk
    __shared__ int stage[TILE];
    int t = threadIdx.x;
    int tile0 = blockIdx.x * TILE;
    int n = E - tile0; if (n > TILE) n = TILE;

    for (int i = t; i < NBMAX; i += 1024) h[i] = 0;
    __syncthreads();
    for (int i = t; i < n; i += 1024)
        atomicAdd(&h[dst[tile0 + i] >> BSH], 1);
    __syncthreads();
    for (int i = t; i < NBMAX; i += 1024) c0[i] = h[i];
    __syncthreads();
    // inclusive Hillis-Steele scan over NBMAX slots (in place, read-sync-write)
    for (int d = 1; d < NBMAX; d <<= 1) {
        int v = (t < NBMAX && t >= d) ? h[t - d] : 0;
        __syncthreads();
        if (t < NBMAX) h[t] += v;
        __syncthreads();
    }
    if (t < NBMAX) { lo[t] = h[t] - c0[t]; cur[t] = h[t] - c0[t]; }
    if (t == 0) lo[NBMAX] = n;
    __syncthreads();
    // reserve global space: one atomic per (block, bucket)
    for (int i = t; i < NB; i += 1024)
        gb[i] = (c0[i] > 0) ? atomicAdd(&gcur[i], c0[i]) : 0;
    __syncthreads();
    // stage packed edges ordered by bucket
    for (int i = t; i < n; i += 1024) {
        int d = dst[tile0 + i];
        int s = src[tile0 + i];
        int b = d >> BSH;
        int p = atomicAdd(&cur[b], 1);
        stage[p] = (s << BSH) | (d & (BRANGE - 1));
    }
    __syncthreads();
    // copy out: contiguous chunk per bucket; binary search bucket of staged slot i
    for (int i = t; i < n; i += 1024) {
        int loB = 0, hiB = NB;          // invariant: lo[loB] <= i < lo[hiB]
        while (hiB - loB > 1) {
            int m = (loB + hiB) >> 1;
            if (lo[m] <= i) loB = m; else hiB = m;
        }
        int b = loB;
        int gpos = gb[b] + (i - lo[b]);
        if (gpos < BCAP)
            part[b * BCAP + gpos] = stage[i];
    }
}

// ============ pass 2: bucket -> padded CSR (one block per bucket; LDS positions) ============
__global__ __launch_bounds__(1024) void k_csr(const int* __restrict__ part,
        const int* __restrict__ gcur, int* __restrict__ csr, int* __restrict__ deg, int N) {
    __shared__ int cnt[BRANGE];
    int b = blockIdx.x, t = threadIdx.x;
    if (t < BRANGE) cnt[t] = 0;
    __syncthreads();
    int cntE = gcur[b]; if (cntE > BCAP) cntE = BCAP;
    const int* pb = part + b * BCAP;
    int n0 = b << BSH;
    for (int i = t; i < cntE; i += 1024) {
        int v = pb[i];
        int d = v & (BRANGE - 1);
        int s = v >> BSH;
        int p = atomicAdd(&cnt[d], 1);              // LDS atomic
        if (p < SLOT)
            csr[(size_t)(n0 + d) * SLOT + p] = s;   // random 4B within 98KB (L2-resident)
    }
    __syncthreads();
    if (t < BRANGE && n0 + t < N) deg[n0 + t] = cnt[t];
}

// ============ one-time transpose W1[512][16] -> W1T[16][512] ============
__global__ __launch_bounds__(256) void k_w1t(const float* __restrict__ W1,
        float* __restrict__ W1T) {
    int t = blockIdx.x * 256 + threadIdx.x;   // 8192 threads
    int k = t >> 4, c = t & 15;
    W1T[c * 512 + k] = W1[t];
}

// ======================= h = relu(x @ W1 + b1), + inv-norm of h =======================
// 4x4 register tile, operands via f32x4 vector loads only (forced residency).
// block = 4 waves = 64 rows; wave q = K-quarter q; lane (rg 0..15, cg 0..3):
// rows {base+rg+16*rr}, cols {4*cg+cc}. Per k4: 8 f32x4 loads + 64 v_fma.
// No LDS / no barrier in main loop; 21.5KB LDS only for the cross-quarter reduce.
__global__ __launch_bounds__(256) void k_gemm1(const float* __restrict__ x,
        const float* __restrict__ W1T, const float* __restrict__ b1,
        float* __restrict__ h, float* __restrict__ invn, int N) {
    __shared__ float red[64 * 4 * 21];   // [rowInBlk][q][16 used of 21]
    int t = threadIdx.x;
    int q = t >> 6, lane = t & 63;
    int rg = lane & 15, cg = lane >> 4;
    int base = blockIdx.x * 64;

    const float* xr0;
    const float* xr1;
    const float* xr2;
    const float* xr3;
    {
        int r0 = base + rg;          if (r0 >= N) r0 = N - 1;
        int r1 = base + rg + 16;     if (r1 >= N) r1 = N - 1;
        int r2 = base + rg + 32;     if (r2 >= N) r2 = N - 1;
        int r3 = base + rg + 48;     if (r3 >= N) r3 = N - 1;
        xr0 = x + (size_t)r0 * 512 + q * 128;
        xr1 = x + (size_t)r1 * 512 + q * 128;
        xr2 = x + (size_t)r2 * 512 + q * 128;
        xr3 = x + (size_t)r3 * 512 + q * 128;
    }
    const float* wc0 = W1T + (cg * 4 + 0) * 512 + q * 128;
    const float* wc1 = W1T + (cg * 4 + 1) * 512 + q * 128;
    const float* wc2 = W1T + (cg * 4 + 2) * 512 + q * 128;
    const float* wc3 = W1T + (cg * 4 + 3) * 512 + q * 128;

    float acc[4][4];
#pragma unroll
    for (int a = 0; a < 4; ++a)
#pragma unroll
        for (int b = 0; b < 4; ++b) acc[a][b] = 0.f;

#pragma unroll 2
    for (int kq = 0; kq < 32; ++kq) {
        f32x4 v0 = *(const f32x4*)(xr0 + kq * 4);
        f32x4 v1 = *(const f32x4*)(xr1 + kq * 4);
        f32x4 v2 = *(const f32x4*)(xr2 + kq * 4);
        f32x4 v3 = *(const f32x4*)(xr3 + kq * 4);
        f32x4 u0 = *(const f32x4*)(wc0 + kq * 4);
        f32x4 u1 = *(const f32x4*)(wc1 + kq * 4);
        f32x4 u2 = *(const f32x4*)(wc2 + kq * 4);
        f32x4 u3 = *(const f32x4*)(wc3 + kq * 4);
#define DOT4(vr, uc) (vr.x*uc.x + vr.y*uc.y + vr.z*uc.z + vr.w*uc.w)
        acc[0][0] += DOT4(v0, u0); acc[0][1] += DOT4(v0, u1);
        acc[0][2] += DOT4(v0, u2); acc[0][3] += DOT4(v0, u3);
        acc[1][0] += DOT4(v1, u0); acc[1][1] += DOT4(v1, u1);
        acc[1][2] += DOT4(v1, u2); acc[1][3] += DOT4(v1, u3);
        acc[2][0] += DOT4(v2, u0); acc[2][1] += DOT4(v2, u1);
        acc[2][2] += DOT4(v2, u2); acc[2][3] += DOT4(v2, u3);
        acc[3][0] += DOT4(v3, u0); acc[3][1] += DOT4(v3, u1);
        acc[3][2] += DOT4(v3, u2); acc[3][3] += DOT4(v3, u3);
#undef DOT4
    }

#pragma unroll
    for (int rr = 0; rr < 4; ++rr) {
        f32x4 w = {acc[rr][0], acc[rr][1], acc[rr][2], acc[rr][3]};
        *(f32x4*)(red + ((rg + 16 * rr) * 4 + q) * 21 + cg * 4) = w;
    }
    __syncthreads();

    // epilogue: thread t -> (rowInBlk = t>>2, cg = t&3); sum the 4 K-quarters
    int row = t >> 2, c4 = t & 3;
    int row2 = base + row;
    f32x4 s = {0.f, 0.f, 0.f, 0.f};
#pragma unroll
    for (int q2 = 0; q2 < 4; ++q2) {
        f32x4 v = *(const f32x4*)(red + (row * 4 + q2) * 21 + c4 * 4);
        s.x += v.x; s.y += v.y; s.z += v.z; s.w += v.w;
    }
    const f32x4 bv = *(const f32x4*)(b1 + c4 * 4);
    s.x = fmaxf(s.x + bv.x, 0.f);
    s.y = fmaxf(s.y + bv.y, 0.f);
    s.z = fmaxf(s.z + bv.z, 0.f);
    s.w = fmaxf(s.w + bv.w, 0.f);
    float ss = s.x * s.x + s.y * s.y + s.z * s.z + s.w * s.w;
    ss += __shfl_xor(ss, 1); ss += __shfl_xor(ss, 2);   // sum over the 4 c4-lanes
    if (row2 < N) {
        *(f32x4*)(h + (size_t)row2 * 16 + c4 * 4) = s;
        if (c4 == 0) invn[row2] = 1.f / fmaxf(sqrtf(ss), EPS_NORM);
    }
}

// ======================= fused AGNN layer (padded-CSR gather, no atomics) =======================
__global__ __launch_bounds__(256) void k_agnn(const float* __restrict__ f,
        const float* __restrict__ inv, const int* __restrict__ deg,
        const int* __restrict__ csr, const float* __restrict__ beta,
        float* __restrict__ fout, float* __restrict__ invout, int N) {
    int wid = (blockIdx.x * 256 + threadIdx.x) >> 6;
    if (wid >= N) return;
    int lane = threadIdx.x & 63;
    int g = lane >> 4, k = lane & 15;

    float fd  = f[(size_t)wid * 16 + k];
    float ivd = inv[wid];
    float b   = beta[0];

    float sd = fd * fd;
    sd += __shfl_xor(sd, 1); sd += __shfl_xor(sd, 2);
    sd += __shfl_xor(sd, 4); sd += __shfl_xor(sd, 8);
    float pself = __expf(b * sd * ivd * ivd);
    float bs = b * ivd;

    int dg = deg[wid];
    int start = wid * SLOT;
    int end   = start + (dg < SLOT ? dg : SLOT);

    float sacc = 0.f, gacc = 0.f;
    for (int e = start + g; e < end; e += 8) {
        int  e1 = e + 4;
        bool v1 = e1 < end;
        int  si0 = csr[e];
        int  si1 = v1 ? csr[e1] : si0;
        float a0 = f[(size_t)si0 * 16 + k];
        float a1 = f[(size_t)si1 * 16 + k];
        float iv0 = inv[si0];
        float iv1 = inv[si1];
        float d0 = a0 * fd, d1 = a1 * fd;
        d0 += __shfl_xor(d0, 1); d1 += __shfl_xor(d1, 1);
        d0 += __shfl_xor(d0, 2); d1 += __shfl_xor(d1, 2);
        d0 += __shfl_xor(d0, 4); d1 += __shfl_xor(d1, 4);
        d0 += __shfl_xor(d0, 8); d1 += __shfl_xor(d1, 8);
        float p0 = __expf(bs * iv0 * d0);
        float p1 = v1 ? __expf(bs * iv1 * d1) : 0.f;
        sacc += p0 + p1;
        gacc += p0 * a0 + p1 * a1;
    }
    sacc += __shfl_xor(sacc, 16); sacc += __shfl_xor(sacc, 32);
    gacc += __shfl_xor(gacc, 16); gacc += __shfl_xor(gacc, 32);

    float denom = sacc + pself + EPS_SM;
    float outk  = (gacc + pself * fd) / denom;

    float ss = outk * outk;
    ss += __shfl_xor(ss, 1); ss += __shfl_xor(ss, 2);
    ss += __shfl_xor(ss, 4); ss += __shfl_xor(ss, 8);

    if (g == 0) {
        fout[(size_t)wid * 16 + k] = outk;
        if (k == 0) invout[wid] = 1.f / fmaxf(sqrtf(ss), EPS_NORM);
    }
}

// ======================= out = softmax(f @ W2 + b2) =======================
__global__ __launch_bounds__(256) void k_out(const float* __restrict__ f,
        const float* __restrict__ W2, const float* __restrict__ b2,
        float* __restrict__ out, int N) {
    __shared__ float w2s[16 * 40];
    __shared__ float b2s[40];
    for (int idx = threadIdx.x; idx < 16 * 40; idx += 256) w2s[idx] = W2[idx];
    if (threadIdx.x < 40) b2s[threadIdx.x] = b2[threadIdx.x];
    __syncthreads();
    int i = blockIdx.x * 256 + threadIdx.x;
    if (i >= N) return;
    const float4* fr = (const float4*)(f + (size_t)i * 16);
    float4 q0 = fr[0], q1 = fr[1], q2 = fr[2], q3 = fr[3];
    float fv[16] = {q0.x, q0.y, q0.z, q0.w, q1.x, q1.y, q1.z, q1.w,
                    q2.x, q2.y, q2.z, q2.w, q3.x, q3.y, q3.z, q3.w};
    float z[40];
#pragma unroll
    for (int c = 0; c < 40; ++c) z[c] = b2s[c];
#pragma unroll
    for (int k = 0; k < 16; ++k) {
        float fk = fv[k];
#pragma unroll
        for (int c = 0; c < 40; ++c) z[c] += fk * w2s[k * 40 + c];
    }
    float m = z[0];
#pragma unroll
    for (int c = 1; c < 40; ++c) m = fmaxf(m, z[c]);
    float ssum = 0.f;
#pragma unroll
    for (int c = 0; c < 40; ++c) { z[c] = __expf(z[c] - m); ssum += z[c]; }
    float is = 1.f / ssum;
    float* orow = out + (size_t)i * 40;
#pragma unroll
    for (int c = 0; c < 40; ++c) orow[c] = z[c] * is;
}

extern "C" void kernel_launch(void* const* d_in, const int* in_sizes, int n_in,
                              void* d_out, int out_size, void* d_ws, size_t ws_size,
                              hipStream_t stream) {
    const float* x    = (const float*)d_in[0];
    const int*   eidx = (const int*)d_in[1];
    const float* W1   = (const float*)d_in[2];
    const float* b1   = (const float*)d_in[3];
    const float* beta[3] = {(const float*)d_in[4], (const float*)d_in[5],
                            (const float*)d_in[6]};
    const float* W2   = (const float*)d_in[7];
    const float* b2   = (const float*)d_in[8];
    float*       out  = (float*)d_out;

    const int FIN = 512, H = 16;
    int N = in_sizes[0] / FIN;
    int E = in_sizes[1] / 2;
    int NB = (N + BRANGE - 1) >> BSH;           // 391 for N=100000

    const int* src = eidx;
    const int* dst = eidx + E;

    // workspace layout: csr[N*SLOT] | deg[N] | gcur[512] | w1t[8192] | part[NB*BCAP]
    // part is dead after k_csr -> overlay f0/f1/inv0/inv1 on it
    int*   csr  = (int*)d_ws;
    int*   degb = csr + (size_t)N * SLOT;
    int*   gcur = degb + N;
    float* w1t  = (float*)(gcur + 512);
    int*   part = (int*)(w1t + 8192);
    float* f0   = (float*)part;
    float* f1   = f0 + (size_t)N * H;
    float* inv0 = f1 + (size_t)N * H;
    float* inv1 = inv0 + N;

    // ---- CSR build: bucket partition (coalesced) + per-bucket LDS-positioned fill
    hipMemsetAsync(gcur, 0, 512 * 4, stream);
    k_w1t<<<dim3(32), dim3(256), 0, stream>>>(W1, w1t);
    k_part<<<dim3((E + TILE - 1) / TILE), dim3(1024), 0, stream>>>(src, dst, gcur, part, E, NB);
    k_csr<<<dim3(NB), dim3(1024), 0, stream>>>(part, gcur, csr, degb, N);

    // ---- MLP in + 3 fused AGNN layers + MLP out  (k_gemm1 overwrites part region)
    k_gemm1<<<dim3((N + 63) / 64), dim3(256), 0, stream>>>(x, w1t, b1, f0, inv0, N);

    float* fin = f0;  float* fout = f1;
    float* ivi = inv0; float* ivo = inv1;
    for (int l = 0; l < 3; ++l) {
        k_agnn<<<dim3((N + 3) / 4), dim3(256), 0, stream>>>(
            fin, ivi, degb, csr, beta[l], fout, ivo, N);
        float* t = fin; fin = fout; fout = t;
        t = ivi; ivi = ivo; ivo = t;
    }
    k_out<<<dim3((N + 255) / 256), dim3(256), 0, stream>>>(fin, W2, b2, out, N);
}